// Round 6
// baseline (457.433 us; speedup 1.0000x reference)
//
#include <hip/hip_runtime.h>
#include <hip/hip_bf16.h>

#define NCOLS 16384
#define DDIM  256
#define TILE  256            // block tile: 256 rows x 256 cols
#define NTI   64             // tiles per dim
#define NBLK  2080           // NTI*(NTI+1)/2 upper-triangle blocks
#define SQRT_L2E 1.2011224087864498f  // sqrt(log2 e); A*B picks up log2(e)

typedef __attribute__((ext_vector_type(8))) short bf16x8;
typedef __attribute__((ext_vector_type(4))) float f32x4;
typedef __attribute__((ext_vector_type(4))) int   i32x4;

static __device__ __forceinline__ ushort f2bf_rne(float f) {
    unsigned u = __builtin_bit_cast(unsigned, f);
    unsigned r = (u + 0x7fffu + ((u >> 16) & 1u)) >> 16;
    return (ushort)r;
}

// ---- Kernel 1: column norm + scale + TRANSPOSED bf16 pack, coalesced both ways.
// 512 blocks x 256 thr; block owns 32 columns; LDS 32-col f32 tile (pad 33).
__global__ __launch_bounds__(256)
void k_norm(const float* __restrict__ W, ushort* __restrict__ wnT,
            float* __restrict__ S) {
    __shared__ float tile[256][33];     // 33.8 KiB
    __shared__ float scr[8][32];
    __shared__ float scale_s[32];
    const int t  = threadIdx.x;
    const int c0 = blockIdx.x * 32;

    // phase 1: coalesced float4 reads -> LDS scatter (4 scalar writes, ~2-way)
    const int q = t & 7, dsub = t >> 3;           // col-quad, row-within-pass
    #pragma unroll
    for (int p = 0; p < 8; ++p) {
        const int d = p * 32 + dsub;
        const float4 v = *reinterpret_cast<const float4*>(
            &W[(size_t)d * NCOLS + c0 + q * 4]);
        tile[d][q * 4 + 0] = v.x; tile[d][q * 4 + 1] = v.y;
        tile[d][q * 4 + 2] = v.z; tile[d][q * 4 + 3] = v.w;
    }
    __syncthreads();

    // phase 2: per-column sum of squares (conflict-free column reads)
    const int c = t & 31, g = t >> 5;
    float p2 = 0.f;
    #pragma unroll
    for (int e = 0; e < 32; ++e) {
        float x = tile[g * 32 + e][c];
        p2 = fmaf(x, x, p2);
    }
    scr[g][c] = p2;
    __syncthreads();
    if (t < 32) {
        float n2 = 0.f;
        #pragma unroll
        for (int k2 = 0; k2 < 8; ++k2) n2 += scr[k2][t];
        scale_s[t] = SQRT_L2E / fmaxf(sqrtf(n2), 1e-8f);
        S[c0 + t] = 0.f;                 // zero row-sum accumulator
    }
    __syncthreads();

    // phase 3: wave w writes col c0+p*4+w; lane l covers d = 4l..4l+3 (8B store)
    const int wv = t >> 6, l = t & 63;
    #pragma unroll
    for (int p = 0; p < 8; ++p) {
        const int cc = p * 4 + wv;
        const float sc = scale_s[cc];
        union { ushort us[4]; uint2 u2; } pk;
        #pragma unroll
        for (int e = 0; e < 4; ++e) pk.us[e] = f2bf_rne(tile[l * 4 + e][cc] * sc);
        *reinterpret_cast<uint2*>(&wnT[(size_t)(c0 + cc) * DDIM + l * 4]) = pk.u2;
    }
}

// ---- Kernel 2: symmetric fused Gram + exp + row/col sums.
// Barrier-free main loop: A resident in regs, B fragments streamed directly
// from global (wnT L2/L3-resident), 2-deep register pipeline, no LDS staging.
__global__ __launch_bounds__(256, 2)
void k_gram(const ushort* __restrict__ wnT, float* __restrict__ S) {
    __shared__ float colLDS[4][256];    // per-wave private col accumulators (4 KiB)

    // decode upper-triangle (ti,tj), row-major
    const int t = blockIdx.x;
    const int u = (NBLK - 1) - t;
    int k = (int)((sqrtf((float)(8 * u + 1)) - 1.0f) * 0.5f);
    while ((k + 1) * (k + 2) / 2 <= u) ++k;
    while (k * (k + 1) / 2 > u) --k;
    const int ti = 63 - k;
    const int tj = 63 - (u - k * (k + 1) / 2);
    const bool diag = (ti == tj);
    const int i0 = ti * TILE, j0 = tj * TILE;

    const int tid  = threadIdx.x;
    const int lane = tid & 63, wave = tid >> 6;
    const int l15  = lane & 15;
    const int kofe = ((lane >> 4) & 3) * 8;       // k element offset (16B chunk)

    // init this wave's private col accumulators (no cross-wave access -> no barrier)
    #pragma unroll
    for (int e = 0; e < 4; ++e) colLDS[wave][lane * 4 + e] = 0.f;

    // A fragments: 4 strips x 8 k-steps, rows i0 + wave*64 + s*16 + l15
    bf16x8 afrag[4][8];
    #pragma unroll
    for (int s = 0; s < 4; ++s) {
        const ushort* arow = wnT + (size_t)(i0 + wave * 64 + s * 16 + l15) * DDIM + kofe;
        #pragma unroll
        for (int kk = 0; kk < 8; ++kk)
            afrag[s][kk] = *reinterpret_cast<const bf16x8*>(arow + kk * 32);
    }

    float rowsum[4][4];
    #pragma unroll
    for (int s = 0; s < 4; ++s)
        #pragma unroll
        for (int r = 0; r < 4; ++r) rowsum[s][r] = 0.f;

    // 2-deep B register pipeline
    bf16x8 b[2][8];
    {
        const ushort* brow = wnT + (size_t)(j0 + l15) * DDIM + kofe;
        #pragma unroll
        for (int kk = 0; kk < 8; ++kk)
            b[0][kk] = *reinterpret_cast<const bf16x8*>(brow + kk * 32);
    }

    #pragma unroll
    for (int jj = 0; jj < 16; ++jj) {
        if (jj < 15) {   // prefetch next jj's fragments (independent of MFMA below)
            const ushort* brow = wnT + (size_t)(j0 + (jj + 1) * 16 + l15) * DDIM + kofe;
            #pragma unroll
            for (int kk = 0; kk < 8; ++kk)
                b[(jj + 1) & 1][kk] = *reinterpret_cast<const bf16x8*>(brow + kk * 32);
        }
        float colpart = 0.f;
        __builtin_amdgcn_s_setprio(1);
        #pragma unroll
        for (int s = 0; s < 4; ++s) {
            f32x4 acc = {0.f, 0.f, 0.f, 0.f};
            #pragma unroll
            for (int kk = 0; kk < 8; ++kk)
                acc = __builtin_amdgcn_mfma_f32_16x16x32_bf16(
                    afrag[s][kk], b[jj & 1][kk], acc, 0, 0, 0);
            __builtin_amdgcn_s_setprio(0);
            #pragma unroll
            for (int r = 0; r < 4; ++r) {
                float e = __builtin_amdgcn_exp2f(acc[r]);   // = exp(G)
                rowsum[s][r] += e;
                colpart      += e;
            }
            __builtin_amdgcn_s_setprio(1);
        }
        __builtin_amdgcn_s_setprio(0);
        // fold column partial: reduce over the 4 row-groups (lane>>4)
        colpart += __shfl_xor(colpart, 16, 64);
        colpart += __shfl_xor(colpart, 32, 64);
        if (lane < 16)
            colLDS[wave][jj * 16 + l15] += colpart;   // wave-private row
    }

    // row sums -> atomics (C layout: col=lane&15, row=(lane>>4)*4+r)
    #pragma unroll
    for (int s = 0; s < 4; ++s)
        #pragma unroll
        for (int r = 0; r < 4; ++r) {
            float v = rowsum[s][r];
            v += __shfl_xor(v, 1, 64);
            v += __shfl_xor(v, 2, 64);
            v += __shfl_xor(v, 4, 64);
            v += __shfl_xor(v, 8, 64);
            if (l15 == 0)
                atomicAdd(&S[i0 + wave * 64 + s * 16 + (lane >> 4) * 4 + r], v);
        }

    // mirrored col sums (off-diag only): combine 4 waves, 1 atomic per column
    __syncthreads();
    if (!diag) {
        const float sum = colLDS[0][tid] + colLDS[1][tid] +
                          colLDS[2][tid] + colLDS[3][tid];
        atomicAdd(&S[j0 + tid], sum);
    }
}

// ---- Kernel 3: loss = lw * (ln2 * sum(log2 S) - N) / N   (the -1 folded here)
__global__ __launch_bounds__(1024)
void k_final(const float* __restrict__ S, const float* __restrict__ lw,
             float* __restrict__ out) {
    float a = 0.f;
    for (int i = threadIdx.x; i < NCOLS; i += 1024)
        a += __builtin_amdgcn_logf(S[i]);          // log2
    #pragma unroll
    for (int m = 1; m < 64; m <<= 1) a += __shfl_xor(a, m, 64);
    __shared__ float red[16];
    if ((threadIdx.x & 63) == 0) red[threadIdx.x >> 6] = a;
    __syncthreads();
    if (threadIdx.x == 0) {
        float tot = 0.f;
        #pragma unroll
        for (int q2 = 0; q2 < 16; ++q2) tot += red[q2];
        out[0] = lw[0] * (tot * 0.6931471805599453f - (float)NCOLS) / (float)NCOLS;
    }
}

extern "C" void kernel_launch(void* const* d_in, const int* in_sizes, int n_in,
                              void* d_out, int out_size, void* d_ws, size_t ws_size,
                              hipStream_t stream) {
    const float* W  = (const float*)d_in[0];
    const float* lw = (const float*)d_in[1];
    float* out = (float*)d_out;

    ushort* wnT = (ushort*)d_ws;                                    // 8 MiB
    float*  S   = (float*)((char*)d_ws + (size_t)NCOLS * DDIM * 2); // 64 KiB

    k_norm <<<NCOLS / 32, 256, 0, stream>>>(W, wnT, S);
    k_gram <<<NBLK, 256, 0, stream>>>(wnT, S);
    k_final<<<1, 1024, 0, stream>>>(S, lw, out);
}

// Round 7
// 212.546 us; speedup vs baseline: 2.1522x; 2.1522x over previous
//
#include <hip/hip_runtime.h>
#include <hip/hip_bf16.h>

#define NCOLS 16384
#define DDIM  256
#define TILE  128            // block tile: 128 rows x 128 cols
#define NTI   128            // tiles per dim
#define NBLK  8256           // NTI*(NTI+1)/2 upper-triangle blocks
#define BN    32             // cols per LDS sub-tile (double-buffered, 4 steps)
#define SQRT_L2E 1.2011224087864498f  // sqrt(log2 e); A*B picks up log2(e)

typedef __attribute__((ext_vector_type(8))) short bf16x8;
typedef __attribute__((ext_vector_type(4))) float f32x4;
typedef __attribute__((ext_vector_type(4))) int   i32x4;

typedef __attribute__((address_space(1))) const unsigned int gu32;
typedef __attribute__((address_space(3))) unsigned int       lu32;

static __device__ __forceinline__ ushort f2bf_rne(float f) {
    unsigned u = __builtin_bit_cast(unsigned, f);
    unsigned r = (u + 0x7fffu + ((u >> 16) & 1u)) >> 16;
    return (ushort)r;
}

// ---- Kernel 1: single-pass column norm + scale + bf16 pack (transposed out).
// 512 blocks x 256 thr; block owns 32 cols; thread caches 32 W values in regs.
__global__ __launch_bounds__(256)
void k_norm(const float* __restrict__ W, ushort* __restrict__ wnT,
            float* __restrict__ S) {
    __shared__ float red[8][32];
    __shared__ float scale_s[32];
    const int tid = threadIdx.x;
    const int il = tid & 31, st = tid >> 5;
    const int col = blockIdx.x * 32 + il;
    float v[32];
    float p = 0.f;
    #pragma unroll
    for (int e = 0; e < 32; ++e) {
        v[e] = W[(size_t)(st * 32 + e) * NCOLS + col];
        p = fmaf(v[e], v[e], p);
    }
    red[st][il] = p;
    __syncthreads();
    if (tid < 32) {
        float n = 0.f;
        #pragma unroll
        for (int q = 0; q < 8; ++q) n += red[q][tid];
        scale_s[tid] = SQRT_L2E / fmaxf(sqrtf(n), 1e-8f);
        S[blockIdx.x * 32 + tid] = 0.f;          // zero row-sum accumulator
    }
    __syncthreads();
    const float sc = scale_s[il];
    #pragma unroll
    for (int g = 0; g < 4; ++g) {
        union { ushort us[8]; i32x4 w4; } pk;
        #pragma unroll
        for (int e2 = 0; e2 < 8; ++e2) pk.us[e2] = f2bf_rne(v[g * 8 + e2] * sc);
        *reinterpret_cast<i32x4*>(&wnT[(size_t)col * DDIM + st * 32 + g * 8]) = pk.w4;
    }
}

// ---- Kernel 2: symmetric fused Gram + exp + row/col sums. 128x128 tiles.
// 4 waves; wave owns 32 rows (afrag[2][8] = 64 VGPR). B double-buffered in
// 2x16 KiB LDS via global_load_lds; XOR swizzle on global SOURCE + LDS READ
// (rule #21), dest linear. Col partials in static registers; atomics at end.
__global__ __launch_bounds__(256, 3)
void k_gram(const ushort* __restrict__ wnT, float* __restrict__ S) {
    __shared__ ushort Bs[2][BN * DDIM];          // 2 x 16 KiB
    __shared__ float colLDS[4][TILE];            // 2 KiB, wave-private rows

    // decode upper-triangle (ti,tj), row-major: (0,0),(0,1)..,(1,1)..
    const int t = blockIdx.x;
    const int u = (NBLK - 1) - t;
    int k = (int)((sqrtf((float)(8 * u + 1)) - 1.0f) * 0.5f);
    while ((k + 1) * (k + 2) / 2 <= u) ++k;
    while (k * (k + 1) / 2 > u) --k;
    const int ti = (NTI - 1) - k;
    const int tj = (NTI - 1) - (u - k * (k + 1) / 2);
    const bool diag = (ti == tj);
    const int i0 = ti * TILE, j0 = tj * TILE;

    const int tid  = threadIdx.x;
    const int lane = tid & 63, wave = tid >> 6;
    const int l15  = lane & 15;
    const int kofe = ((lane >> 4) & 3) * 8;      // k element offset (16B chunk)
    const int xorm = (lane & 7) << 4;            // read-side swizzle

    // A fragments: 2 strips x 8 k-steps, rows i0 + wave*32 + s*16 + l15
    bf16x8 afrag[2][8];
    #pragma unroll
    for (int s = 0; s < 2; ++s) {
        const ushort* arow = wnT + (size_t)(i0 + wave * 32 + s * 16 + l15) * DDIM + kofe;
        #pragma unroll
        for (int kk = 0; kk < 8; ++kk)
            afrag[s][kk] = *reinterpret_cast<const bf16x8*>(arow + kk * 32);
    }

    // stage sub-tile jt into Bs[b]: 4 insts/wave, 2 cols (512B) per inst.
    auto stage = [&](int b, int jt2) {
        #pragma unroll
        for (int q = 0; q < 4; ++q) {
            const int r0  = wave * 8 + q * 2;
            const int row = r0 + (lane >> 5);
            const int sb  = ((lane & 31) * 16) ^ ((row & 7) << 4);
            const ushort* g = wnT + (size_t)(j0 + jt2 * BN + row) * DDIM + (sb >> 1);
            char* l = (char*)&Bs[b][0] + (r0 << 9);   // wave-uniform dest
            __builtin_amdgcn_global_load_lds((gu32*)g, (lu32*)l, 16, 0, 0);
        }
    };

    float rowsum[2][4];
    float colacc[8];
    #pragma unroll
    for (int s = 0; s < 2; ++s)
        #pragma unroll
        for (int r = 0; r < 4; ++r) rowsum[s][r] = 0.f;
    #pragma unroll
    for (int c = 0; c < 8; ++c) colacc[c] = 0.f;

    stage(0, 0);
    __syncthreads();

    #pragma unroll
    for (int jt = 0; jt < 4; ++jt) {
        if (jt < 3) stage((jt + 1) & 1, jt + 1);     // prefetch overlaps compute
        const char* bufbase = (const char*)&Bs[jt & 1][0];
        #pragma unroll
        for (int jj = 0; jj < 2; ++jj) {
            const char* brow = bufbase + ((jj * 16 + l15) << 9);
            bf16x8 b[8];
            #pragma unroll
            for (int kk = 0; kk < 8; ++kk)
                b[kk] = *reinterpret_cast<const bf16x8*>(
                    brow + ((kk * 64 + kofe * 2) ^ xorm));
            __builtin_amdgcn_s_setprio(1);
            #pragma unroll
            for (int s = 0; s < 2; ++s) {
                f32x4 acc = {0.f, 0.f, 0.f, 0.f};
                #pragma unroll
                for (int kk = 0; kk < 8; ++kk)
                    acc = __builtin_amdgcn_mfma_f32_16x16x32_bf16(
                        afrag[s][kk], b[kk], acc, 0, 0, 0);
                __builtin_amdgcn_s_setprio(0);
                #pragma unroll
                for (int r = 0; r < 4; ++r) {
                    float e = __builtin_amdgcn_exp2f(acc[r]);   // = exp(G)
                    rowsum[s][r]        += e;
                    colacc[jt * 2 + jj] += e;
                }
                __builtin_amdgcn_s_setprio(1);
            }
            __builtin_amdgcn_s_setprio(0);
        }
        __syncthreads();         // staging landed + all reads of cur buf done
    }

    // row sums -> atomics (C layout: col=lane&15, row=(lane>>4)*4+r)
    #pragma unroll
    for (int s = 0; s < 2; ++s)
        #pragma unroll
        for (int r = 0; r < 4; ++r) {
            float v = rowsum[s][r];
            v += __shfl_xor(v, 1, 64);
            v += __shfl_xor(v, 2, 64);
            v += __shfl_xor(v, 4, 64);
            v += __shfl_xor(v, 8, 64);
            if (l15 == 0)
                atomicAdd(&S[i0 + wave * 32 + s * 16 + (lane >> 4) * 4 + r], v);
        }

    // mirrored col sums: wave-reduce groups, LDS combine, 1 atomic per column
    #pragma unroll
    for (int c = 0; c < 8; ++c) {
        float v = colacc[c];
        v += __shfl_xor(v, 16, 64);
        v += __shfl_xor(v, 32, 64);
        if (lane < 16) colLDS[wave][c * 16 + l15] = v;
    }
    __syncthreads();
    if (!diag && tid < TILE) {
        const float sum = colLDS[0][tid] + colLDS[1][tid] +
                          colLDS[2][tid] + colLDS[3][tid];
        atomicAdd(&S[j0 + tid], sum);
    }
}

// ---- Kernel 3: loss = lw * (ln2 * sum(log2 S) - N) / N   (the -1 folded here)
__global__ __launch_bounds__(1024)
void k_final(const float* __restrict__ S, const float* __restrict__ lw,
             float* __restrict__ out) {
    float a = 0.f;
    for (int i = threadIdx.x; i < NCOLS; i += 1024)
        a += __builtin_amdgcn_logf(S[i]);          // log2
    #pragma unroll
    for (int m = 1; m < 64; m <<= 1) a += __shfl_xor(a, m, 64);
    __shared__ float red[16];
    if ((threadIdx.x & 63) == 0) red[threadIdx.x >> 6] = a;
    __syncthreads();
    if (threadIdx.x == 0) {
        float tot = 0.f;
        #pragma unroll
        for (int q2 = 0; q2 < 16; ++q2) tot += red[q2];
        out[0] = lw[0] * (tot * 0.6931471805599453f - (float)NCOLS) / (float)NCOLS;
    }
}

extern "C" void kernel_launch(void* const* d_in, const int* in_sizes, int n_in,
                              void* d_out, int out_size, void* d_ws, size_t ws_size,
                              hipStream_t stream) {
    const float* W  = (const float*)d_in[0];
    const float* lw = (const float*)d_in[1];
    float* out = (float*)d_out;

    ushort* wnT = (ushort*)d_ws;                                    // 8 MiB
    float*  S   = (float*)((char*)d_ws + (size_t)NCOLS * DDIM * 2); // 64 KiB

    k_norm <<<NCOLS / 32, 256, 0, stream>>>(W, wnT, S);
    k_gram <<<NBLK, 256, 0, stream>>>(wnT, S);
    k_final<<<1, 1024, 0, stream>>>(S, lw, out);
}